// Round 1
// baseline (83.959 us; speedup 1.0000x reference)
//
#include <hip/hip_runtime.h>
#include <math.h>

#define TPB 256
#define B_TOTAL 524288

__global__ __launch_bounds__(TPB) void logic_net_kernel(
    const float* __restrict__ state,        // [B,18]
    const float* __restrict__ c_templates,  // [12,2]
    const float* __restrict__ c_gammas,     // [12,2]
    const float* __restrict__ a_templates,  // [6,2,2]
    const float* __restrict__ a_gammas,     // [6,2,2]
    const float* __restrict__ a_body_W,     // [6,2,4,2]
    const float* __restrict__ a_body_b,     // [6,2,4]
    const float* __restrict__ a_head_W,     // [6,2,4]
    const float* __restrict__ a_head_b,     // [6,2]
    const float* __restrict__ act_W,        // [9,12]
    const float* __restrict__ act_b,        // [9]
    float* __restrict__ out)                // [B,9]
{
    __shared__ float s_state[TPB * 18];     // 18 KiB
    __shared__ float s_ct[24], s_cw[24];    // templates, 1-clip(gamma)
    __shared__ float s_at[24], s_aw[24];
    __shared__ float s_bW[96], s_bb[48];
    __shared__ float s_hW[48], s_hb[12];
    __shared__ float s_actW[108], s_actb[9];

    const int tid = threadIdx.x;

    // ---- stage state tile (coalesced float4) ----
    {
        const float4* gs = (const float4*)(state + (size_t)blockIdx.x * (TPB * 18));
        float4* ls = (float4*)s_state;
        #pragma unroll
        for (int k = 0; k < 5; ++k) {
            int idx = tid + k * TPB;
            if (idx < TPB * 18 / 4) ls[idx] = gs[idx];
        }
    }

    // ---- stage weights (tiny, once per block) ----
    if (tid < 24) {
        s_ct[tid] = c_templates[tid];
        float g = fminf(fmaxf(c_gammas[tid], 0.f), 1.f);
        s_cw[tid] = 1.f - g;
        s_at[tid] = a_templates[tid];
        float g2 = fminf(fmaxf(a_gammas[tid], 0.f), 1.f);
        s_aw[tid] = 1.f - g2;
    }
    if (tid < 96)  s_bW[tid]   = a_body_W[tid];
    if (tid < 48)  s_bb[tid]   = a_body_b[tid];
    if (tid < 48)  s_hW[tid]   = a_head_W[tid];
    if (tid < 12)  s_hb[tid]   = a_head_b[tid];
    if (tid < 108) s_actW[tid] = act_W[tid];
    if (tid < 9)   s_actb[tid] = act_b[tid];

    __syncthreads();

    // ---- load my board [9][2] from LDS ----
    const float* st = &s_state[tid * 18];
    float b0[9], b1[9];
    #pragma unroll
    for (int i = 0; i < 9; ++i) { b0[i] = st[2 * i]; b1[i] = st[2 * i + 1]; }

    // ---- ConcreteLayer: 12 rules ----
    float cf0[12], cf1[12];
    #pragma unroll
    for (int r = 0; r < 12; ++r) {
        const float t0 = s_ct[2 * r], t1 = s_ct[2 * r + 1];
        const float w0 = s_cw[2 * r], w1 = s_cw[2 * r + 1];
        float ms[9];
        float mn = 1e30f;
        #pragma unroll
        for (int i = 0; i < 9; ++i) {
            float d0 = t0 - b0[i], d1 = t1 - b1[i];
            float m = d0 * d0 * w0 + d1 * d1 * w1;
            ms[i] = m;
            mn = fminf(mn, m);
        }
        float se = 0.f, s1 = 0.f;
        #pragma unroll
        for (int i = 0; i < 9; ++i) {
            float e = __expf(mn - ms[i]);   // softmax(-ms) with max-subtract
            se += e;
            s1 += e * b1[i];
        }
        cf0[r] = __expf(-mn);               // pattern_strength
        cf1[r] = s1 / se;                   // matched[...,1]
    }

    // ---- AbstractionLayer: 6 rules x 2 clauses ----
    float flat[12];
    #pragma unroll
    for (int r = 0; r < 6; ++r) {
        float cap[4] = {0.f, 0.f, 0.f, 0.f};
        #pragma unroll
        for (int j = 0; j < 2; ++j) {
            const int rj = r * 2 + j;
            const float t0 = s_at[2 * rj], t1 = s_at[2 * rj + 1];
            const float w0 = s_aw[2 * rj], w1 = s_aw[2 * rj + 1];
            float ms[12];
            float mn = 1e30f;
            #pragma unroll
            for (int i = 0; i < 12; ++i) {
                float d0 = t0 - cf0[i], d1 = t1 - cf1[i];
                float m = d0 * d0 * w0 + d1 * d1 * w1;
                ms[i] = m;
                mn = fminf(mn, m);
            }
            float se = 0.f, q0 = 0.f, q1 = 0.f;
            #pragma unroll
            for (int i = 0; i < 12; ++i) {
                float e = __expf(mn - ms[i]);
                se += e;
                q0 += e * cf0[i];
                q1 += e * cf1[i];
            }
            float inv = 1.f / se;
            float sel0 = q0 * inv, sel1 = q1 * inv;
            #pragma unroll
            for (int v = 0; v < 4; ++v) {
                cap[v] += s_bW[rj * 8 + v * 2] * sel0
                        + s_bW[rj * 8 + v * 2 + 1] * sel1
                        + s_bb[rj * 4 + v];
            }
        }
        #pragma unroll
        for (int l = 0; l < 2; ++l) {
            float c = s_hb[r * 2 + l];
            #pragma unroll
            for (int v = 0; v < 4; ++v) c += cap[v] * s_hW[(r * 2 + l) * 4 + v];
            flat[r * 2 + l] = c;
        }
    }

    // ---- ActionLayer ----
    const size_t ob = ((size_t)blockIdx.x * TPB + tid) * 9;
    #pragma unroll
    for (int a = 0; a < 9; ++a) {
        float q = s_actb[a];
        #pragma unroll
        for (int k = 0; k < 12; ++k) q += flat[k] * s_actW[a * 12 + k];
        out[ob + a] = q;
    }
}

extern "C" void kernel_launch(void* const* d_in, const int* in_sizes, int n_in,
                              void* d_out, int out_size, void* d_ws, size_t ws_size,
                              hipStream_t stream) {
    const float* state       = (const float*)d_in[0];
    const float* c_templates = (const float*)d_in[1];
    const float* c_gammas    = (const float*)d_in[2];
    const float* a_templates = (const float*)d_in[3];
    const float* a_gammas    = (const float*)d_in[4];
    const float* a_body_W    = (const float*)d_in[5];
    const float* a_body_b    = (const float*)d_in[6];
    const float* a_head_W    = (const float*)d_in[7];
    const float* a_head_b    = (const float*)d_in[8];
    const float* act_W       = (const float*)d_in[9];
    const float* act_b       = (const float*)d_in[10];
    float* out = (float*)d_out;

    const int blocks = B_TOTAL / TPB;  // 2048
    logic_net_kernel<<<blocks, TPB, 0, stream>>>(
        state, c_templates, c_gammas, a_templates, a_gammas,
        a_body_W, a_body_b, a_head_W, a_head_b, act_W, act_b, out);
}

// Round 2
// 45.230 us; speedup vs baseline: 1.8563x; 1.8563x over previous
//
#include <hip/hip_runtime.h>
#include <math.h>

#define TPB 256
#define B_TOTAL 524288
#define L2E 1.44269504088896340736f

#if __has_builtin(__builtin_amdgcn_exp2f)
#define EXP2(x) __builtin_amdgcn_exp2f(x)
#else
#define EXP2(x) exp2f(x)
#endif
#define RCP(x) __builtin_amdgcn_rcpf(x)

__global__ __launch_bounds__(TPB) void logic_net_kernel(
    const float* __restrict__ state,        // [B,18]
    const float* __restrict__ c_templates,  // [12,2]
    const float* __restrict__ c_gammas,     // [12,2]
    const float* __restrict__ a_templates,  // [6,2,2]
    const float* __restrict__ a_gammas,     // [6,2,2]
    const float* __restrict__ a_body_W,     // [6,2,4,2]
    const float* __restrict__ a_body_b,     // [6,2,4]
    const float* __restrict__ a_head_W,     // [6,2,4]
    const float* __restrict__ a_head_b,     // [6,2]
    const float* __restrict__ act_W,        // [9,12]
    const float* __restrict__ act_b,        // [9]
    float* __restrict__ out)                // [B,9]
{
    __shared__ float s_state[TPB * 18];  // 18 KiB
    // Folded constants, all in exp2-space:
    // e = exp(-ms) = exp2(A + w0*x0^2 + w1*x1^2 + c0*x0 + c1*x1)
    __shared__ float sC[60];   // concrete: per rule {A, -W0, -W1, 2W0t0, 2W1t1}, W=(1-g)*L2E
    __shared__ float sA[60];   // abstraction: per clause, same 5
    __shared__ float sP[216];  // folded (body W)*(head W)*(act W): [(rj*9+a)*2+p]
    __shared__ float sQ0[9];   // folded bias: act_b + actW*(head_b + headW*sum_j body_b)

    const int tid = threadIdx.x;

    // ---- stage state tile (coalesced float4) ----
    {
        const float4* gs = (const float4*)(state + (size_t)blockIdx.x * (TPB * 18));
        float4* ls = (float4*)s_state;
        #pragma unroll
        for (int k = 0; k < 5; ++k) {
            int idx = tid + k * TPB;
            if (idx < TPB * 18 / 4) ls[idx] = gs[idx];
        }
    }

    // ---- fold constants, once per block, fully parallel ----
    if (tid < 12) {
        int r = tid;
        float t0 = c_templates[2*r], t1 = c_templates[2*r+1];
        float g0 = fminf(fmaxf(c_gammas[2*r],   0.f), 1.f);
        float g1 = fminf(fmaxf(c_gammas[2*r+1], 0.f), 1.f);
        float W0 = (1.f - g0) * L2E, W1 = (1.f - g1) * L2E;
        sC[5*r+0] = -(W0*t0*t0 + W1*t1*t1);
        sC[5*r+1] = -W0;
        sC[5*r+2] = -W1;
        sC[5*r+3] = 2.f*W0*t0;
        sC[5*r+4] = 2.f*W1*t1;
    } else if (tid < 24) {
        int rj = tid - 12;
        float t0 = a_templates[2*rj], t1 = a_templates[2*rj+1];
        float g0 = fminf(fmaxf(a_gammas[2*rj],   0.f), 1.f);
        float g1 = fminf(fmaxf(a_gammas[2*rj+1], 0.f), 1.f);
        float W0 = (1.f - g0) * L2E, W1 = (1.f - g1) * L2E;
        sA[5*rj+0] = -(W0*t0*t0 + W1*t1*t1);
        sA[5*rj+1] = -W0;
        sA[5*rj+2] = -W1;
        sA[5*rj+3] = 2.f*W0*t0;
        sA[5*rj+4] = 2.f*W1*t1;
    } else if (tid < 240) {
        int m = tid - 24;             // 0..215
        int a = m / 24;
        int rem = m % 24;
        int rj = rem / 2, p = rem % 2;
        int r = rj / 2;
        float s = 0.f;
        #pragma unroll
        for (int l = 0; l < 2; ++l) {
            float M = 0.f;
            #pragma unroll
            for (int v = 0; v < 4; ++v)
                M += a_head_W[(r*2+l)*4 + v] * a_body_W[(rj*4 + v)*2 + p];
            s += act_W[a*12 + 2*r + l] * M;
        }
        sP[(rj*9 + a)*2 + p] = s;
    } else if (tid < 249) {
        int a = tid - 240;
        float s = act_b[a];
        #pragma unroll
        for (int r = 0; r < 6; ++r) {
            #pragma unroll
            for (int l = 0; l < 2; ++l) {
                float h = a_head_b[r*2 + l];
                #pragma unroll
                for (int v = 0; v < 4; ++v)
                    h += a_head_W[(r*2+l)*4 + v] *
                         (a_body_b[(r*2)*4 + v] + a_body_b[(r*2+1)*4 + v]);
                s += act_W[a*12 + 2*r + l] * h;
            }
        }
        sQ0[a] = s;
    }

    __syncthreads();

    // ---- per-thread row ----
    const float* st = &s_state[tid * 18];
    float b0[9], b1[9], u0[9], u1[9];
    #pragma unroll
    for (int i = 0; i < 9; ++i) {
        b0[i] = st[2*i];
        b1[i] = st[2*i + 1];
        u0[i] = b0[i] * b0[i];
        u1[i] = b1[i] * b1[i];
    }

    // ---- ConcreteLayer: single-pass softmax, e_i = exp(-ms_i), strength = max e_i ----
    float cf0[12], cf1[12];
    #pragma unroll
    for (int r = 0; r < 12; ++r) {
        const float A  = sC[5*r+0];
        const float w0 = sC[5*r+1], w1 = sC[5*r+2];
        const float c0 = sC[5*r+3], c1 = sC[5*r+4];
        float mx = 0.f, se = 0.f, s1 = 0.f;
        #pragma unroll
        for (int i = 0; i < 9; ++i) {
            float t = fmaf(c1, b1[i], A);
            t = fmaf(c0, b0[i], t);
            t = fmaf(w1, u1[i], t);
            t = fmaf(w0, u0[i], t);
            float e = EXP2(t);
            mx = fmaxf(mx, e);
            se += e;
            s1 = fmaf(e, b1[i], s1);
        }
        cf0[r] = mx;                 // exp(-min ms) == max exp(-ms)
        cf1[r] = s1 * RCP(se);
    }

    // ---- AbstractionLayer + folded head/action ----
    float v0[12], v1[12];
    #pragma unroll
    for (int i = 0; i < 12; ++i) {
        v0[i] = cf0[i] * cf0[i];
        v1[i] = cf1[i] * cf1[i];
    }

    float q[9];
    #pragma unroll
    for (int a = 0; a < 9; ++a) q[a] = sQ0[a];

    #pragma unroll
    for (int rj = 0; rj < 12; ++rj) {
        const float A  = sA[5*rj+0];
        const float w0 = sA[5*rj+1], w1 = sA[5*rj+2];
        const float c0 = sA[5*rj+3], c1 = sA[5*rj+4];
        float se = 0.f, q0 = 0.f, q1 = 0.f;
        #pragma unroll
        for (int i = 0; i < 12; ++i) {
            float t = fmaf(c1, cf1[i], A);
            t = fmaf(c0, cf0[i], t);
            t = fmaf(w1, v1[i], t);
            t = fmaf(w0, v0[i], t);
            float e = EXP2(t);
            se += e;
            q0 = fmaf(e, cf0[i], q0);
            q1 = fmaf(e, cf1[i], q1);
        }
        float inv = RCP(se);
        float sel0 = q0 * inv, sel1 = q1 * inv;
        #pragma unroll
        for (int a = 0; a < 9; ++a) {
            q[a] = fmaf(sel0, sP[(rj*9 + a)*2 + 0],
                   fmaf(sel1, sP[(rj*9 + a)*2 + 1], q[a]));
        }
    }

    // ---- store ----
    const size_t ob = ((size_t)blockIdx.x * TPB + tid) * 9;
    #pragma unroll
    for (int a = 0; a < 9; ++a) out[ob + a] = q[a];
}

extern "C" void kernel_launch(void* const* d_in, const int* in_sizes, int n_in,
                              void* d_out, int out_size, void* d_ws, size_t ws_size,
                              hipStream_t stream) {
    const float* state       = (const float*)d_in[0];
    const float* c_templates = (const float*)d_in[1];
    const float* c_gammas    = (const float*)d_in[2];
    const float* a_templates = (const float*)d_in[3];
    const float* a_gammas    = (const float*)d_in[4];
    const float* a_body_W    = (const float*)d_in[5];
    const float* a_body_b    = (const float*)d_in[6];
    const float* a_head_W    = (const float*)d_in[7];
    const float* a_head_b    = (const float*)d_in[8];
    const float* act_W       = (const float*)d_in[9];
    const float* act_b       = (const float*)d_in[10];
    float* out = (float*)d_out;

    const int blocks = B_TOTAL / TPB;  // 2048
    logic_net_kernel<<<blocks, TPB, 0, stream>>>(
        state, c_templates, c_gammas, a_templates, a_gammas,
        a_body_W, a_body_b, a_head_W, a_head_b, act_W, act_b, out);
}

// Round 3
// 34.512 us; speedup vs baseline: 2.4328x; 1.3106x over previous
//
#include <hip/hip_runtime.h>
#include <math.h>

#define TPB 256
#define B_TOTAL 524288
#define L2E 1.44269504088896340736f

#if __has_builtin(__builtin_amdgcn_exp2f)
#define EXP2(x) __builtin_amdgcn_exp2f(x)
#else
#define EXP2(x) exp2f(x)
#endif
#define RCP(x) __builtin_amdgcn_rcpf(x)

typedef float v2f __attribute__((ext_vector_type(2)));

__device__ __forceinline__ v2f bc(float s) { return (v2f){s, s}; }
__device__ __forceinline__ v2f pkfma(v2f a, v2f b, v2f c) {
    return __builtin_elementwise_fma(a, b, c);
}

__global__ __launch_bounds__(TPB) void logic_net_kernel(
    const float* __restrict__ state,        // [B,18]
    const float* __restrict__ c_templates,  // [12,2]
    const float* __restrict__ c_gammas,     // [12,2]
    const float* __restrict__ a_templates,  // [6,2,2]
    const float* __restrict__ a_gammas,     // [6,2,2]
    const float* __restrict__ a_body_W,     // [6,2,4,2]
    const float* __restrict__ a_body_b,     // [6,2,4]
    const float* __restrict__ a_head_W,     // [6,2,4]
    const float* __restrict__ a_head_b,     // [6,2]
    const float* __restrict__ act_W,        // [9,12]
    const float* __restrict__ act_b,        // [9]
    float* __restrict__ out)                // [B,9]
{
    // Folded constants in exp2-space; packed over rule/clause PAIRS.
    // e = exp(-ms) = exp2(A + w0*x0^2 + w1*x1^2 + c0*x0 + c1*x1)
    __shared__ alignas(16) float sCc[60];   // [rp][k][half]: rp*10 + k*2 + half; k={A,w0,w1,c0,c1}
    __shared__ alignas(16) float sAa[60];   // same for abstraction clauses
    __shared__ alignas(16) float sM[48];    // M[rj][p][l] = sum_v headW[r,l,v]*bodyW[rj,v,p]; idx rj*4+p*2+l
    __shared__ alignas(16) float sAW[120];  // awp[rl][ap][half]: (rl*5+ap)*2+half, action a=2ap+half (a=9 -> 0)
    __shared__ alignas(16) float sQ0[10];   // folded bias per action (padded)

    const int tid = threadIdx.x;

    // ---- fold constants, once per block, fully parallel, disjoint thread ranges ----
    if (tid < 12) {
        int r = tid;
        float t0 = c_templates[2*r], t1 = c_templates[2*r+1];
        float g0 = fminf(fmaxf(c_gammas[2*r],   0.f), 1.f);
        float g1 = fminf(fmaxf(c_gammas[2*r+1], 0.f), 1.f);
        float W0 = (1.f - g0) * L2E, W1 = (1.f - g1) * L2E;
        int b = (r >> 1) * 10, h = r & 1;
        sCc[b + 0 + h] = -(W0*t0*t0 + W1*t1*t1);
        sCc[b + 2 + h] = -W0;
        sCc[b + 4 + h] = -W1;
        sCc[b + 6 + h] = 2.f*W0*t0;
        sCc[b + 8 + h] = 2.f*W1*t1;
    } else if (tid < 24) {
        int rj = tid - 12;
        float t0 = a_templates[2*rj], t1 = a_templates[2*rj+1];
        float g0 = fminf(fmaxf(a_gammas[2*rj],   0.f), 1.f);
        float g1 = fminf(fmaxf(a_gammas[2*rj+1], 0.f), 1.f);
        float W0 = (1.f - g0) * L2E, W1 = (1.f - g1) * L2E;
        int b = (rj >> 1) * 10, h = rj & 1;
        sAa[b + 0 + h] = -(W0*t0*t0 + W1*t1*t1);
        sAa[b + 2 + h] = -W0;
        sAa[b + 4 + h] = -W1;
        sAa[b + 6 + h] = 2.f*W0*t0;
        sAa[b + 8 + h] = 2.f*W1*t1;
    } else if (tid < 72) {
        int m = tid - 24;              // 0..47
        int rj = m >> 2, p = (m >> 1) & 1, l = m & 1, r = rj >> 1;
        float s = 0.f;
        #pragma unroll
        for (int v = 0; v < 4; ++v)
            s += a_head_W[(r*2 + l)*4 + v] * a_body_W[(rj*4 + v)*2 + p];
        sM[m] = s;
    } else if (tid < 192) {
        int m = tid - 72;              // 0..119
        int rl = m / 10, rem = m % 10;
        int a = rem;                   // a = 2*ap + half = rem
        sAW[m] = (a < 9) ? act_W[a*12 + rl] : 0.f;
    } else if (tid < 201) {
        int a = tid - 192;
        float s = act_b[a];
        #pragma unroll
        for (int r = 0; r < 6; ++r) {
            #pragma unroll
            for (int l = 0; l < 2; ++l) {
                float h = a_head_b[r*2 + l];
                #pragma unroll
                for (int v = 0; v < 4; ++v)
                    h += a_head_W[(r*2+l)*4 + v] *
                         (a_body_b[(r*2)*4 + v] + a_body_b[(r*2+1)*4 + v]);
                s += act_W[a*12 + 2*r + l] * h;
            }
        }
        sQ0[a] = s;
    } else if (tid == 201) {
        sQ0[9] = 0.f;
    }

    __syncthreads();

    // ---- per-thread row: direct global loads, 9 x dwordx2 ----
    const int row = blockIdx.x * TPB + tid;
    const float* st = state + (size_t)row * 18;
    v2f p[9], u[9];
    #pragma unroll
    for (int i = 0; i < 9; ++i) {
        p[i] = *(const v2f*)(st + 2*i);   // {b0_i, b1_i}
        u[i] = p[i] * p[i];               // {b0^2, b1^2}  (v_pk_mul_f32)
    }

    // ---- ConcreteLayer: packed over rule pairs ----
    v2f cf0p[6], cf1p[6];
    #pragma unroll
    for (int rp = 0; rp < 6; ++rp) {
        const v2f A2  = *(const v2f*)&sCc[rp*10 + 0];
        const v2f W02 = *(const v2f*)&sCc[rp*10 + 2];
        const v2f W12 = *(const v2f*)&sCc[rp*10 + 4];
        const v2f C02 = *(const v2f*)&sCc[rp*10 + 6];
        const v2f C12 = *(const v2f*)&sCc[rp*10 + 8];
        v2f mx2 = (v2f){0.f, 0.f}, se2 = (v2f){0.f, 0.f}, s12 = (v2f){0.f, 0.f};
        #pragma unroll
        for (int i = 0; i < 9; ++i) {
            v2f t2 = pkfma(W02, bc(u[i].x), A2);
            t2 = pkfma(W12, bc(u[i].y), t2);
            t2 = pkfma(C02, bc(p[i].x), t2);
            t2 = pkfma(C12, bc(p[i].y), t2);
            v2f e2 = (v2f){EXP2(t2.x), EXP2(t2.y)};
            mx2 = __builtin_elementwise_max(mx2, e2);
            se2 += e2;
            s12 = pkfma(e2, bc(p[i].y), s12);
        }
        cf0p[rp] = mx2;                        // pattern_strength = max e
        cf1p[rp] = s12 * (v2f){RCP(se2.x), RCP(se2.y)};
    }

    // ---- AbstractionLayer: packed over clause pairs (pair cp = clauses of rule cp) ----
    v2f v0p[6], v1p[6];
    #pragma unroll
    for (int k = 0; k < 6; ++k) { v0p[k] = cf0p[k] * cf0p[k]; v1p[k] = cf1p[k] * cf1p[k]; }

    v2f y2[6];
    #pragma unroll
    for (int cp = 0; cp < 6; ++cp) {
        const v2f A2  = *(const v2f*)&sAa[cp*10 + 0];
        const v2f W02 = *(const v2f*)&sAa[cp*10 + 2];
        const v2f W12 = *(const v2f*)&sAa[cp*10 + 4];
        const v2f C02 = *(const v2f*)&sAa[cp*10 + 6];
        const v2f C12 = *(const v2f*)&sAa[cp*10 + 8];
        v2f se2 = (v2f){0.f, 0.f}, q02 = (v2f){0.f, 0.f}, q12 = (v2f){0.f, 0.f};
        #pragma unroll
        for (int i = 0; i < 12; ++i) {
            const float c0 = cf0p[i >> 1][i & 1];
            const float c1 = cf1p[i >> 1][i & 1];
            v2f t2 = pkfma(W02, bc(v0p[i >> 1][i & 1]), A2);
            t2 = pkfma(W12, bc(v1p[i >> 1][i & 1]), t2);
            t2 = pkfma(C02, bc(c0), t2);
            t2 = pkfma(C12, bc(c1), t2);
            v2f e2 = (v2f){EXP2(t2.x), EXP2(t2.y)};
            se2 += e2;
            q02 = pkfma(e2, bc(c0), q02);
            q12 = pkfma(e2, bc(c1), q12);
        }
        v2f inv2  = (v2f){RCP(se2.x), RCP(se2.y)};
        v2f sel02 = q02 * inv2;                // {sel0 of clause 2cp, sel0 of clause 2cp+1}
        v2f sel12 = q12 * inv2;
        // y[r=cp][l-pair] = sum over the 2 clauses, 2 inputs of sel * M
        v2f y = bc(sel02.x) * (*(const v2f*)&sM[(2*cp)*4 + 0]);
        y = pkfma(bc(sel12.x), *(const v2f*)&sM[(2*cp)*4 + 2], y);
        y = pkfma(bc(sel02.y), *(const v2f*)&sM[(2*cp+1)*4 + 0], y);
        y = pkfma(bc(sel12.y), *(const v2f*)&sM[(2*cp+1)*4 + 2], y);
        y2[cp] = y;
    }

    // ---- ActionLayer: q[a] = Q0[a] + sum_rl actW[a,rl] * y[rl]; packed over action pairs ----
    v2f Q[5];
    #pragma unroll
    for (int ap = 0; ap < 5; ++ap) Q[ap] = *(const v2f*)&sQ0[ap*2];
    #pragma unroll
    for (int rl = 0; rl < 12; ++rl) {
        const v2f yv = bc(y2[rl >> 1][rl & 1]);
        #pragma unroll
        for (int ap = 0; ap < 5; ++ap)
            Q[ap] = pkfma(yv, *(const v2f*)&sAW[(rl*5 + ap)*2], Q[ap]);
    }

    // ---- store 9 floats ----
    float* op = out + (size_t)row * 9;
    #pragma unroll
    for (int a = 0; a < 9; ++a) op[a] = Q[a >> 1][a & 1];
}

extern "C" void kernel_launch(void* const* d_in, const int* in_sizes, int n_in,
                              void* d_out, int out_size, void* d_ws, size_t ws_size,
                              hipStream_t stream) {
    const float* state       = (const float*)d_in[0];
    const float* c_templates = (const float*)d_in[1];
    const float* c_gammas    = (const float*)d_in[2];
    const float* a_templates = (const float*)d_in[3];
    const float* a_gammas    = (const float*)d_in[4];
    const float* a_body_W    = (const float*)d_in[5];
    const float* a_body_b    = (const float*)d_in[6];
    const float* a_head_W    = (const float*)d_in[7];
    const float* a_head_b    = (const float*)d_in[8];
    const float* act_W       = (const float*)d_in[9];
    const float* act_b       = (const float*)d_in[10];
    float* out = (float*)d_out;

    const int blocks = B_TOTAL / TPB;  // 2048
    logic_net_kernel<<<blocks, TPB, 0, stream>>>(
        state, c_templates, c_gammas, a_templates, a_gammas,
        a_body_W, a_body_b, a_head_W, a_head_b, act_W, act_b, out);
}